// Round 1
// baseline (1662.883 us; speedup 1.0000x reference)
//
#include <hip/hip_runtime.h>
#include <math.h>

#define IN_FEATS 128
#define OUT_FEATS 64
#define NEG_SLOPE 0.2f

// ---------------------------------------------------------------------------
// K1: h[n][o] = sum_k feat[n][k] * W[o][k]
// One wave per node; lane o holds W[o][:] in 128 VGPRs (W is 32KB total).
// feat row loads are wave-uniform -> broadcast from L1.
// ---------------------------------------------------------------------------
__global__ void gemm_h_kernel(const float* __restrict__ feat,
                              const float* __restrict__ W,
                              float* __restrict__ h, int n_nodes) {
  const int lane = threadIdx.x & 63;
  const int waves_per_block = blockDim.x >> 6;
  int wave = blockIdx.x * waves_per_block + (threadIdx.x >> 6);
  const int nwaves = gridDim.x * waves_per_block;

  float4 w[32];
  const float4* Wv = reinterpret_cast<const float4*>(W + lane * IN_FEATS);
#pragma unroll
  for (int i = 0; i < 32; ++i) w[i] = Wv[i];

  for (int n = wave; n < n_nodes; n += nwaves) {
    const float4* fv = reinterpret_cast<const float4*>(feat + (size_t)n * IN_FEATS);
    float acc = 0.f;
#pragma unroll
    for (int i = 0; i < 32; ++i) {
      float4 f = fv[i];
      acc = fmaf(f.x, w[i].x, acc);
      acc = fmaf(f.y, w[i].y, acc);
      acc = fmaf(f.z, w[i].z, acc);
      acc = fmaf(f.w, w[i].w, acc);
    }
    h[(size_t)n * OUT_FEATS + lane] = acc;
  }
}

// ---------------------------------------------------------------------------
// init m = -inf, s = 0
// ---------------------------------------------------------------------------
__global__ void init_ms_kernel(float* __restrict__ m, float* __restrict__ s, int n) {
  int i = blockIdx.x * blockDim.x + threadIdx.x;
  if (i < n) { m[i] = -INFINITY; s[i] = 0.f; }
}

// ---------------------------------------------------------------------------
// K2: h_agg[dst[e]][f] += h[src[e]][f]   (wave per edge, lane per feature)
// Gather and atomic target are each 256B contiguous per edge.
// ---------------------------------------------------------------------------
__global__ void scatter_kernel(const float* __restrict__ h,
                               const int* __restrict__ src,
                               const int* __restrict__ dst,
                               float* __restrict__ h_agg, int n_edges) {
  long long t = (long long)blockIdx.x * blockDim.x + threadIdx.x;
  int e = (int)(t >> 6);
  int f = (int)(t & 63);
  if (e >= n_edges) return;
  int s = src[e];
  int d = dst[e];
  atomicAdd(&h_agg[(size_t)d * OUT_FEATS + f], h[(size_t)s * OUT_FEATS + f]);
}

// ---------------------------------------------------------------------------
// K3: t_agg = tanh(h_agg), elementwise (6.4M instead of 102M tanh in K4)
// ---------------------------------------------------------------------------
__global__ void tanh_kernel(const float* __restrict__ h_agg,
                            float* __restrict__ t_agg, int n) {
  int i = blockIdx.x * blockDim.x + threadIdx.x;
  if (i < n) t_agg[i] = tanhf(h_agg[i]);
}

// ---------------------------------------------------------------------------
// K4: e[edge] = leaky_relu( sum_f h_agg[src][f] * t_agg[dst][f] )
//     and m[dst] = segment max (float atomic-max via int/uint trick)
// ---------------------------------------------------------------------------
__global__ void score_kernel(const float* __restrict__ h_agg,
                             const float* __restrict__ t_agg,
                             const int* __restrict__ src,
                             const int* __restrict__ dst,
                             float* __restrict__ e_out,
                             float* __restrict__ m, int n_edges) {
  long long t = (long long)blockIdx.x * blockDim.x + threadIdx.x;
  int e = (int)(t >> 6);
  int f = (int)(t & 63);
  if (e >= n_edges) return;
  int s = src[e];
  int d = dst[e];
  float v = h_agg[(size_t)s * OUT_FEATS + f] * t_agg[(size_t)d * OUT_FEATS + f];
#pragma unroll
  for (int off = 32; off > 0; off >>= 1) v += __shfl_xor(v, off, 64);
  if (f == 0) {
    v = v > 0.f ? v : NEG_SLOPE * v;
    e_out[e] = v;
    // float atomic max: monotone int mapping (init is -inf)
    if (v >= 0.f) atomicMax((int*)&m[d], __float_as_int(v));
    else          atomicMin((unsigned int*)&m[d], __float_as_uint(v));
  }
}

// ---------------------------------------------------------------------------
// K5: ex = exp(e - m[dst]); s[dst] += ex  (in-place on e_soft slot)
// ---------------------------------------------------------------------------
__global__ void exp_kernel(float* __restrict__ e_io,
                           const int* __restrict__ dst,
                           const float* __restrict__ m,
                           float* __restrict__ s, int n_edges) {
  int e = blockIdx.x * blockDim.x + threadIdx.x;
  if (e < n_edges) {
    int d = dst[e];
    float ex = expf(e_io[e] - m[d]);
    e_io[e] = ex;
    atomicAdd(&s[d], ex);
  }
}

// ---------------------------------------------------------------------------
// K6: e_soft = ex / s[dst]
// ---------------------------------------------------------------------------
__global__ void div_kernel(float* __restrict__ e_io,
                           const int* __restrict__ dst,
                           const float* __restrict__ s, int n_edges) {
  int e = blockIdx.x * blockDim.x + threadIdx.x;
  if (e < n_edges) e_io[e] = e_io[e] / s[dst[e]];
}

extern "C" void kernel_launch(void* const* d_in, const int* in_sizes, int n_in,
                              void* d_out, int out_size, void* d_ws, size_t ws_size,
                              hipStream_t stream) {
  const float* feat = (const float*)d_in[0];
  const float* W    = (const float*)d_in[1];
  const int*   src  = (const int*)d_in[2];
  const int*   dst  = (const int*)d_in[3];
  const int n_nodes = in_sizes[0] / IN_FEATS;
  const int n_edges = in_sizes[2];

  // Output layout: [h_agg (N*64) | e_soft (E)]
  float* h_agg  = (float*)d_out;
  float* e_soft = (float*)d_out + (size_t)n_nodes * OUT_FEATS;

  // Workspace layout: [h / t_agg (N*64) | m (N) | s (N)]
  float* h = (float*)d_ws;
  float* m = h + (size_t)n_nodes * OUT_FEATS;
  float* s = m + n_nodes;

  // zero the h_agg slice of the output (accumulated via atomics)
  hipMemsetAsync(d_out, 0, (size_t)n_nodes * OUT_FEATS * sizeof(float), stream);

  init_ms_kernel<<<(n_nodes + 255) / 256, 256, 0, stream>>>(m, s, n_nodes);

  gemm_h_kernel<<<(n_nodes + 3) / 4, 256, 0, stream>>>(feat, W, h, n_nodes);

  long long scatter_threads = (long long)n_edges * 64;
  int sb = (int)((scatter_threads + 255) / 256);
  scatter_kernel<<<sb, 256, 0, stream>>>(h, src, dst, h_agg, n_edges);

  int nt = n_nodes * OUT_FEATS;
  tanh_kernel<<<(nt + 255) / 256, 256, 0, stream>>>(h_agg, h, nt);  // t_agg reuses h

  score_kernel<<<sb, 256, 0, stream>>>(h_agg, h, src, dst, e_soft, m, n_edges);

  int eb = (n_edges + 255) / 256;
  exp_kernel<<<eb, 256, 0, stream>>>(e_soft, dst, m, s, n_edges);
  div_kernel<<<eb, 256, 0, stream>>>(e_soft, dst, s, n_edges);
}

// Round 2
// 852.097 us; speedup vs baseline: 1.9515x; 1.9515x over previous
//
#include <hip/hip_runtime.h>
#include <math.h>

#define IN_FEATS 128
#define OUT_FEATS 64
#define NEG_SLOPE 0.2f

// ---------------------------------------------------------------------------
// K1: h[n][o] = sum_k feat[n][k] * W[o][k]
// Lane-per-node: each lane holds its node's feat row in 128 VGPRs.
// W accesses are wave-uniform (uniform loop indices) -> scalar s_load,
// shared across all 64 lanes, no vector traffic and no per-lane W regs.
// ---------------------------------------------------------------------------
__global__ __launch_bounds__(256, 2)
void gemm_h_kernel(const float* __restrict__ feat,
                   const float* __restrict__ W,
                   float* __restrict__ h, int n_nodes) {
  const int n = blockIdx.x * blockDim.x + threadIdx.x;
  if (n >= n_nodes) return;

  // load this node's feature row into registers (contiguous per lane -> L1)
  float4 f[32];
  const float4* fv = reinterpret_cast<const float4*>(feat + (size_t)n * IN_FEATS);
#pragma unroll
  for (int i = 0; i < 32; ++i) f[i] = fv[i];

  float* hrow = h + (size_t)n * OUT_FEATS;
  for (int ob = 0; ob < OUT_FEATS / 4; ++ob) {
    const float* __restrict__ w0 = W + (size_t)(ob * 4 + 0) * IN_FEATS;
    const float* __restrict__ w1 = W + (size_t)(ob * 4 + 1) * IN_FEATS;
    const float* __restrict__ w2 = W + (size_t)(ob * 4 + 2) * IN_FEATS;
    const float* __restrict__ w3 = W + (size_t)(ob * 4 + 3) * IN_FEATS;
    float a0 = 0.f, a1 = 0.f, a2 = 0.f, a3 = 0.f;
#pragma unroll
    for (int i = 0; i < 32; ++i) {
      float4 fk = f[i];
      a0 = fmaf(fk.x, w0[4 * i + 0], a0);
      a0 = fmaf(fk.y, w0[4 * i + 1], a0);
      a0 = fmaf(fk.z, w0[4 * i + 2], a0);
      a0 = fmaf(fk.w, w0[4 * i + 3], a0);
      a1 = fmaf(fk.x, w1[4 * i + 0], a1);
      a1 = fmaf(fk.y, w1[4 * i + 1], a1);
      a1 = fmaf(fk.z, w1[4 * i + 2], a1);
      a1 = fmaf(fk.w, w1[4 * i + 3], a1);
      a2 = fmaf(fk.x, w2[4 * i + 0], a2);
      a2 = fmaf(fk.y, w2[4 * i + 1], a2);
      a2 = fmaf(fk.z, w2[4 * i + 2], a2);
      a2 = fmaf(fk.w, w2[4 * i + 3], a2);
      a3 = fmaf(fk.x, w3[4 * i + 0], a3);
      a3 = fmaf(fk.y, w3[4 * i + 1], a3);
      a3 = fmaf(fk.z, w3[4 * i + 2], a3);
      a3 = fmaf(fk.w, w3[4 * i + 3], a3);
    }
    float4 out;
    out.x = a0; out.y = a1; out.z = a2; out.w = a3;
    *reinterpret_cast<float4*>(hrow + ob * 4) = out;
  }
}

// ---------------------------------------------------------------------------
// init m = -inf, s = 0
// ---------------------------------------------------------------------------
__global__ void init_ms_kernel(float* __restrict__ m, float* __restrict__ s, int n) {
  int i = blockIdx.x * blockDim.x + threadIdx.x;
  if (i < n) { m[i] = -INFINITY; s[i] = 0.f; }
}

// ---------------------------------------------------------------------------
// K2: h_agg[dst[e]][f] += h[src[e]][f]   (wave per edge, lane per feature)
// ---------------------------------------------------------------------------
__global__ void scatter_kernel(const float* __restrict__ h,
                               const int* __restrict__ src,
                               const int* __restrict__ dst,
                               float* __restrict__ h_agg, int n_edges) {
  long long t = (long long)blockIdx.x * blockDim.x + threadIdx.x;
  int e = (int)(t >> 6);
  int f = (int)(t & 63);
  if (e >= n_edges) return;
  int s = src[e];
  int d = dst[e];
  atomicAdd(&h_agg[(size_t)d * OUT_FEATS + f], h[(size_t)s * OUT_FEATS + f]);
}

// ---------------------------------------------------------------------------
// K3: t_agg = tanh(h_agg), elementwise
// ---------------------------------------------------------------------------
__global__ void tanh_kernel(const float* __restrict__ h_agg,
                            float* __restrict__ t_agg, int n) {
  int i = blockIdx.x * blockDim.x + threadIdx.x;
  if (i < n) t_agg[i] = tanhf(h_agg[i]);
}

// ---------------------------------------------------------------------------
// K4: e[edge] = leaky_relu( sum_f h_agg[src][f] * t_agg[dst][f] )
//     and m[dst] = segment max (float atomic-max via int/uint trick)
// ---------------------------------------------------------------------------
__global__ void score_kernel(const float* __restrict__ h_agg,
                             const float* __restrict__ t_agg,
                             const int* __restrict__ src,
                             const int* __restrict__ dst,
                             float* __restrict__ e_out,
                             float* __restrict__ m, int n_edges) {
  long long t = (long long)blockIdx.x * blockDim.x + threadIdx.x;
  int e = (int)(t >> 6);
  int f = (int)(t & 63);
  if (e >= n_edges) return;
  int s = src[e];
  int d = dst[e];
  float v = h_agg[(size_t)s * OUT_FEATS + f] * t_agg[(size_t)d * OUT_FEATS + f];
#pragma unroll
  for (int off = 32; off > 0; off >>= 1) v += __shfl_xor(v, off, 64);
  if (f == 0) {
    v = v > 0.f ? v : NEG_SLOPE * v;
    e_out[e] = v;
    if (v >= 0.f) atomicMax((int*)&m[d], __float_as_int(v));
    else          atomicMin((unsigned int*)&m[d], __float_as_uint(v));
  }
}

// ---------------------------------------------------------------------------
// K5: ex = exp(e - m[dst]); s[dst] += ex
// ---------------------------------------------------------------------------
__global__ void exp_kernel(float* __restrict__ e_io,
                           const int* __restrict__ dst,
                           const float* __restrict__ m,
                           float* __restrict__ s, int n_edges) {
  int e = blockIdx.x * blockDim.x + threadIdx.x;
  if (e < n_edges) {
    int d = dst[e];
    float ex = expf(e_io[e] - m[d]);
    e_io[e] = ex;
    atomicAdd(&s[d], ex);
  }
}

// ---------------------------------------------------------------------------
// K6: e_soft = ex / s[dst]
// ---------------------------------------------------------------------------
__global__ void div_kernel(float* __restrict__ e_io,
                           const int* __restrict__ dst,
                           const float* __restrict__ s, int n_edges) {
  int e = blockIdx.x * blockDim.x + threadIdx.x;
  if (e < n_edges) e_io[e] = e_io[e] / s[dst[e]];
}

extern "C" void kernel_launch(void* const* d_in, const int* in_sizes, int n_in,
                              void* d_out, int out_size, void* d_ws, size_t ws_size,
                              hipStream_t stream) {
  const float* feat = (const float*)d_in[0];
  const float* W    = (const float*)d_in[1];
  const int*   src  = (const int*)d_in[2];
  const int*   dst  = (const int*)d_in[3];
  const int n_nodes = in_sizes[0] / IN_FEATS;
  const int n_edges = in_sizes[2];

  // Output layout: [h_agg (N*64) | e_soft (E)]
  float* h_agg  = (float*)d_out;
  float* e_soft = (float*)d_out + (size_t)n_nodes * OUT_FEATS;

  // Workspace layout: [h / t_agg (N*64) | m (N) | s (N)]
  float* h = (float*)d_ws;
  float* m = h + (size_t)n_nodes * OUT_FEATS;
  float* s = m + n_nodes;

  hipMemsetAsync(d_out, 0, (size_t)n_nodes * OUT_FEATS * sizeof(float), stream);

  init_ms_kernel<<<(n_nodes + 255) / 256, 256, 0, stream>>>(m, s, n_nodes);

  gemm_h_kernel<<<(n_nodes + 255) / 256, 256, 0, stream>>>(feat, W, h, n_nodes);

  long long scatter_threads = (long long)n_edges * 64;
  int sb = (int)((scatter_threads + 255) / 256);
  scatter_kernel<<<sb, 256, 0, stream>>>(h, src, dst, h_agg, n_edges);

  int nt = n_nodes * OUT_FEATS;
  tanh_kernel<<<(nt + 255) / 256, 256, 0, stream>>>(h_agg, h, nt);  // t_agg reuses h

  score_kernel<<<sb, 256, 0, stream>>>(h_agg, h, src, dst, e_soft, m, n_edges);

  int eb = (n_edges + 255) / 256;
  exp_kernel<<<eb, 256, 0, stream>>>(e_soft, dst, m, s, n_edges);
  div_kernel<<<eb, 256, 0, stream>>>(e_soft, dst, s, n_edges);
}

// Round 3
// 655.818 us; speedup vs baseline: 2.5356x; 1.2993x over previous
//
#include <hip/hip_runtime.h>
#include <math.h>

#define IN_FEATS 128
#define OUT_FEATS 64
#define NEG_SLOPE 0.2f
#define MAXD 256

// ---------------------------------------------------------------------------
// K1: h[n][o] = sum_k feat[n][k] * W[o][k]
// Lane-per-node; W accesses wave-uniform -> scalar loads.
// ---------------------------------------------------------------------------
__global__ __launch_bounds__(256, 2)
void gemm_h_kernel(const float* __restrict__ feat,
                   const float* __restrict__ W,
                   float* __restrict__ h, int n_nodes) {
  const int n = blockIdx.x * blockDim.x + threadIdx.x;
  if (n >= n_nodes) return;

  float4 f[32];
  const float4* fv = reinterpret_cast<const float4*>(feat + (size_t)n * IN_FEATS);
#pragma unroll
  for (int i = 0; i < 32; ++i) f[i] = fv[i];

  float* hrow = h + (size_t)n * OUT_FEATS;
  for (int ob = 0; ob < OUT_FEATS / 4; ++ob) {
    const float* __restrict__ w0 = W + (size_t)(ob * 4 + 0) * IN_FEATS;
    const float* __restrict__ w1 = W + (size_t)(ob * 4 + 1) * IN_FEATS;
    const float* __restrict__ w2 = W + (size_t)(ob * 4 + 2) * IN_FEATS;
    const float* __restrict__ w3 = W + (size_t)(ob * 4 + 3) * IN_FEATS;
    float a0 = 0.f, a1 = 0.f, a2 = 0.f, a3 = 0.f;
#pragma unroll
    for (int i = 0; i < 32; ++i) {
      float4 fk = f[i];
      a0 = fmaf(fk.x, w0[4*i+0], a0); a0 = fmaf(fk.y, w0[4*i+1], a0);
      a0 = fmaf(fk.z, w0[4*i+2], a0); a0 = fmaf(fk.w, w0[4*i+3], a0);
      a1 = fmaf(fk.x, w1[4*i+0], a1); a1 = fmaf(fk.y, w1[4*i+1], a1);
      a1 = fmaf(fk.z, w1[4*i+2], a1); a1 = fmaf(fk.w, w1[4*i+3], a1);
      a2 = fmaf(fk.x, w2[4*i+0], a2); a2 = fmaf(fk.y, w2[4*i+1], a2);
      a2 = fmaf(fk.z, w2[4*i+2], a2); a2 = fmaf(fk.w, w2[4*i+3], a2);
      a3 = fmaf(fk.x, w3[4*i+0], a3); a3 = fmaf(fk.y, w3[4*i+1], a3);
      a3 = fmaf(fk.z, w3[4*i+2], a3); a3 = fmaf(fk.w, w3[4*i+3], a3);
    }
    float4 out; out.x = a0; out.y = a1; out.z = a2; out.w = a3;
    *reinterpret_cast<float4*>(hrow + ob * 4) = out;
  }
}

// ---------------------------------------------------------------------------
// CSR build: histogram -> 3-kernel exclusive scan -> bin
// ---------------------------------------------------------------------------
__global__ void hist_kernel(const int* __restrict__ dst, int* __restrict__ deg,
                            int n_edges) {
  int e = blockIdx.x * blockDim.x + threadIdx.x;
  if (e < n_edges) atomicAdd(&deg[dst[e]], 1);
}

__global__ void scan1_kernel(const int* __restrict__ deg, int* __restrict__ bsum,
                             int n) {
  __shared__ int tmp[256];
  int i = blockIdx.x * 256 + threadIdx.x;
  tmp[threadIdx.x] = (i < n) ? deg[i] : 0;
  __syncthreads();
  for (int off = 128; off > 0; off >>= 1) {
    if (threadIdx.x < off) tmp[threadIdx.x] += tmp[threadIdx.x + off];
    __syncthreads();
  }
  if (threadIdx.x == 0) bsum[blockIdx.x] = tmp[0];
}

__global__ void scan2_kernel(int* __restrict__ bsum, int nb) {
  __shared__ int tmp[1024];
  int t = threadIdx.x;
  int v = (t < nb) ? bsum[t] : 0;
  tmp[t] = v;
  __syncthreads();
  for (int off = 1; off < 1024; off <<= 1) {
    int x = (t >= off) ? tmp[t - off] : 0;
    __syncthreads();
    tmp[t] += x;
    __syncthreads();
  }
  if (t < nb) bsum[t] = tmp[t] - v;  // exclusive
}

__global__ void scan3_kernel(const int* __restrict__ deg, const int* __restrict__ bsum,
                             int* __restrict__ row_ptr, int* __restrict__ cursor,
                             int n, int n_edges) {
  __shared__ int tmp[256];
  int i = blockIdx.x * 256 + threadIdx.x;
  int v = (i < n) ? deg[i] : 0;
  tmp[threadIdx.x] = v;
  __syncthreads();
  for (int off = 1; off < 256; off <<= 1) {
    int x = (threadIdx.x >= off) ? tmp[threadIdx.x - off] : 0;
    __syncthreads();
    tmp[threadIdx.x] += x;
    __syncthreads();
  }
  if (i < n) {
    int excl = tmp[threadIdx.x] - v + bsum[blockIdx.x];
    row_ptr[i] = excl;
    cursor[i]  = excl;
  }
  if (i == 0) row_ptr[n] = n_edges;
}

__global__ void bin_kernel(const int* __restrict__ src, const int* __restrict__ dst,
                           int* __restrict__ cursor, int* __restrict__ esrc,
                           int* __restrict__ eid, int n_edges) {
  int e = blockIdx.x * blockDim.x + threadIdx.x;
  if (e < n_edges) {
    int d = dst[e];
    int pos = atomicAdd(&cursor[d], 1);
    esrc[pos] = src[e];
    eid[pos]  = e;
  }
}

// ---------------------------------------------------------------------------
// agg: wave per node, lane per feature; no atomics.
// ---------------------------------------------------------------------------
__global__ void agg_kernel(const float* __restrict__ h, const int* __restrict__ row_ptr,
                           const int* __restrict__ esrc, float* __restrict__ h_agg,
                           int n_nodes) {
  int wid  = (blockIdx.x * blockDim.x + threadIdx.x) >> 6;
  int lane = threadIdx.x & 63;
  if (wid >= n_nodes) return;
  int beg = row_ptr[wid], end = row_ptr[wid + 1];
  float acc = 0.f;
  for (int i = beg; i < end; ++i) {
    int s = esrc[i];
    acc += h[(size_t)s * OUT_FEATS + lane];
  }
  h_agg[(size_t)wid * OUT_FEATS + lane] = acc;
}

// ---------------------------------------------------------------------------
// fused per-node edge softmax: scores + leaky_relu + max + exp + sum + write
// ---------------------------------------------------------------------------
__global__ __launch_bounds__(256)
void softmax_kernel(const float* __restrict__ h_agg, const int* __restrict__ row_ptr,
                    const int* __restrict__ esrc, const int* __restrict__ eid,
                    float* __restrict__ e_soft, int n_nodes) {
  __shared__ float ebuf[4][MAXD];
  int wid  = (blockIdx.x * blockDim.x + threadIdx.x) >> 6;
  int lane = threadIdx.x & 63;
  int lw   = threadIdx.x >> 6;
  if (wid >= n_nodes) return;
  int beg = row_ptr[wid], end = row_ptr[wid + 1];
  int deg = end - beg;
  if (deg == 0) return;

  float t = tanhf(h_agg[(size_t)wid * OUT_FEATS + lane]);

  if (deg <= MAXD) {
    for (int i = 0; i < deg; ++i) {
      int s = esrc[beg + i];
      float v = h_agg[(size_t)s * OUT_FEATS + lane] * t;
#pragma unroll
      for (int off = 32; off > 0; off >>= 1) v += __shfl_xor(v, off, 64);
      v = v > 0.f ? v : NEG_SLOPE * v;
      if (lane == 0) ebuf[lw][i] = v;
    }
    float mx = -INFINITY;
    for (int i = lane; i < deg; i += 64) mx = fmaxf(mx, ebuf[lw][i]);
#pragma unroll
    for (int off = 32; off > 0; off >>= 1) mx = fmaxf(mx, __shfl_xor(mx, off, 64));
    float sum = 0.f;
    for (int i = lane; i < deg; i += 64) {
      float ex = expf(ebuf[lw][i] - mx);
      ebuf[lw][i] = ex;
      sum += ex;
    }
#pragma unroll
    for (int off = 32; off > 0; off >>= 1) sum += __shfl_xor(sum, off, 64);
    float inv = 1.f / sum;
    for (int i = lane; i < deg; i += 64) e_soft[eid[beg + i]] = ebuf[lw][i] * inv;
  } else {
    // recompute fallback (statistically never hit: Poisson(16) degrees)
    float mx = -INFINITY;
    for (int i = 0; i < deg; ++i) {
      int s = esrc[beg + i];
      float v = h_agg[(size_t)s * OUT_FEATS + lane] * t;
#pragma unroll
      for (int off = 32; off > 0; off >>= 1) v += __shfl_xor(v, off, 64);
      v = v > 0.f ? v : NEG_SLOPE * v;
      mx = fmaxf(mx, v);
    }
    float sum = 0.f;
    for (int i = 0; i < deg; ++i) {
      int s = esrc[beg + i];
      float v = h_agg[(size_t)s * OUT_FEATS + lane] * t;
#pragma unroll
      for (int off = 32; off > 0; off >>= 1) v += __shfl_xor(v, off, 64);
      v = v > 0.f ? v : NEG_SLOPE * v;
      sum += expf(v - mx);
    }
    float inv = 1.f / sum;
    for (int i = 0; i < deg; ++i) {
      int s = esrc[beg + i];
      float v = h_agg[(size_t)s * OUT_FEATS + lane] * t;
#pragma unroll
      for (int off = 32; off > 0; off >>= 1) v += __shfl_xor(v, off, 64);
      v = v > 0.f ? v : NEG_SLOPE * v;
      if (lane == 0) e_soft[eid[beg + i]] = expf(v - mx) * inv;
    }
  }
}

extern "C" void kernel_launch(void* const* d_in, const int* in_sizes, int n_in,
                              void* d_out, int out_size, void* d_ws, size_t ws_size,
                              hipStream_t stream) {
  const float* feat = (const float*)d_in[0];
  const float* W    = (const float*)d_in[1];
  const int*   src  = (const int*)d_in[2];
  const int*   dst  = (const int*)d_in[3];
  const int n_nodes = in_sizes[0] / IN_FEATS;
  const int n_edges = in_sizes[2];

  // Output layout: [h_agg (N*64) | e_soft (E)]
  float* h_agg  = (float*)d_out;
  float* e_soft = (float*)d_out + (size_t)n_nodes * OUT_FEATS;

  // Workspace: [h (N*64 f32) | deg (N) | row_ptr (N+1) | cursor (N) | bsum (1024) | esrc (E) | eid (E)]
  float* h      = (float*)d_ws;
  int* deg      = (int*)(h + (size_t)n_nodes * OUT_FEATS);
  int* row_ptr  = deg + n_nodes;
  int* cursor   = row_ptr + (n_nodes + 1);
  int* bsum     = cursor + n_nodes;
  int* esrc     = bsum + 1024;
  int* eid      = esrc + n_edges;

  const int nb = (n_nodes + 255) / 256;   // 391 blocks; scan2 handles nb<=1024
  const int eb = (n_edges + 255) / 256;
  const int wb = (n_nodes * 64 + 255) / 256;  // wave-per-node grids

  hipMemsetAsync(deg, 0, (size_t)n_nodes * sizeof(int), stream);

  gemm_h_kernel<<<(n_nodes + 255) / 256, 256, 0, stream>>>(feat, W, h, n_nodes);

  hist_kernel<<<eb, 256, 0, stream>>>(dst, deg, n_edges);
  scan1_kernel<<<nb, 256, 0, stream>>>(deg, bsum, n_nodes);
  scan2_kernel<<<1, 1024, 0, stream>>>(bsum, nb);
  scan3_kernel<<<nb, 256, 0, stream>>>(deg, bsum, row_ptr, cursor, n_nodes, n_edges);
  bin_kernel<<<eb, 256, 0, stream>>>(src, dst, cursor, esrc, eid, n_edges);

  agg_kernel<<<wb, 256, 0, stream>>>(h, row_ptr, esrc, h_agg, n_nodes);
  softmax_kernel<<<wb, 256, 0, stream>>>(h_agg, row_ptr, esrc, eid, e_soft, n_nodes);
}

// Round 4
// 475.119 us; speedup vs baseline: 3.4999x; 1.3803x over previous
//
#include <hip/hip_runtime.h>
#include <math.h>

#define IN_FEATS 128
#define OUT_FEATS 64
#define NEG_SLOPE 0.2f
#define MAXD 256

// ---------------------------------------------------------------------------
// K1: h[n][o] = sum_k feat[n][k] * W[o][k]
// Lane-per-node; W accesses wave-uniform -> scalar loads.
// ---------------------------------------------------------------------------
__global__ __launch_bounds__(256, 2)
void gemm_h_kernel(const float* __restrict__ feat,
                   const float* __restrict__ W,
                   float* __restrict__ h, int n_nodes) {
  const int n = blockIdx.x * blockDim.x + threadIdx.x;
  if (n >= n_nodes) return;

  float4 f[32];
  const float4* fv = reinterpret_cast<const float4*>(feat + (size_t)n * IN_FEATS);
#pragma unroll
  for (int i = 0; i < 32; ++i) f[i] = fv[i];

  float* hrow = h + (size_t)n * OUT_FEATS;
  for (int ob = 0; ob < OUT_FEATS / 4; ++ob) {
    const float* __restrict__ w0 = W + (size_t)(ob * 4 + 0) * IN_FEATS;
    const float* __restrict__ w1 = W + (size_t)(ob * 4 + 1) * IN_FEATS;
    const float* __restrict__ w2 = W + (size_t)(ob * 4 + 2) * IN_FEATS;
    const float* __restrict__ w3 = W + (size_t)(ob * 4 + 3) * IN_FEATS;
    float a0 = 0.f, a1 = 0.f, a2 = 0.f, a3 = 0.f;
#pragma unroll
    for (int i = 0; i < 32; ++i) {
      float4 fk = f[i];
      a0 = fmaf(fk.x, w0[4*i+0], a0); a0 = fmaf(fk.y, w0[4*i+1], a0);
      a0 = fmaf(fk.z, w0[4*i+2], a0); a0 = fmaf(fk.w, w0[4*i+3], a0);
      a1 = fmaf(fk.x, w1[4*i+0], a1); a1 = fmaf(fk.y, w1[4*i+1], a1);
      a1 = fmaf(fk.z, w1[4*i+2], a1); a1 = fmaf(fk.w, w1[4*i+3], a1);
      a2 = fmaf(fk.x, w2[4*i+0], a2); a2 = fmaf(fk.y, w2[4*i+1], a2);
      a2 = fmaf(fk.z, w2[4*i+2], a2); a2 = fmaf(fk.w, w2[4*i+3], a2);
      a3 = fmaf(fk.x, w3[4*i+0], a3); a3 = fmaf(fk.y, w3[4*i+1], a3);
      a3 = fmaf(fk.z, w3[4*i+2], a3); a3 = fmaf(fk.w, w3[4*i+3], a3);
    }
    float4 out; out.x = a0; out.y = a1; out.z = a2; out.w = a3;
    *reinterpret_cast<float4*>(hrow + ob * 4) = out;
  }
}

// ---------------------------------------------------------------------------
// CSR build: histogram -> 3-kernel exclusive scan -> bin (packed int2)
// ---------------------------------------------------------------------------
__global__ void hist_kernel(const int* __restrict__ dst, int* __restrict__ deg,
                            int n_edges) {
  int e = blockIdx.x * blockDim.x + threadIdx.x;
  if (e < n_edges) atomicAdd(&deg[dst[e]], 1);
}

__global__ void scan1_kernel(const int* __restrict__ deg, int* __restrict__ bsum,
                             int n) {
  __shared__ int tmp[256];
  int i = blockIdx.x * 256 + threadIdx.x;
  tmp[threadIdx.x] = (i < n) ? deg[i] : 0;
  __syncthreads();
  for (int off = 128; off > 0; off >>= 1) {
    if (threadIdx.x < off) tmp[threadIdx.x] += tmp[threadIdx.x + off];
    __syncthreads();
  }
  if (threadIdx.x == 0) bsum[blockIdx.x] = tmp[0];
}

__global__ void scan2_kernel(int* __restrict__ bsum, int nb) {
  __shared__ int tmp[1024];
  int t = threadIdx.x;
  int v = (t < nb) ? bsum[t] : 0;
  tmp[t] = v;
  __syncthreads();
  for (int off = 1; off < 1024; off <<= 1) {
    int x = (t >= off) ? tmp[t - off] : 0;
    __syncthreads();
    tmp[t] += x;
    __syncthreads();
  }
  if (t < nb) bsum[t] = tmp[t] - v;  // exclusive
}

__global__ void scan3_kernel(const int* __restrict__ deg, const int* __restrict__ bsum,
                             int* __restrict__ row_ptr, int* __restrict__ cursor,
                             int n, int n_edges) {
  __shared__ int tmp[256];
  int i = blockIdx.x * 256 + threadIdx.x;
  int v = (i < n) ? deg[i] : 0;
  tmp[threadIdx.x] = v;
  __syncthreads();
  for (int off = 1; off < 256; off <<= 1) {
    int x = (threadIdx.x >= off) ? tmp[threadIdx.x - off] : 0;
    __syncthreads();
    tmp[threadIdx.x] += x;
    __syncthreads();
  }
  if (i < n) {
    int excl = tmp[threadIdx.x] - v + bsum[blockIdx.x];
    row_ptr[i] = excl;
    cursor[i]  = excl;
  }
  if (i == 0) row_ptr[n] = n_edges;
}

__global__ void bin_kernel(const int* __restrict__ src, const int* __restrict__ dst,
                           int* __restrict__ cursor, int2* __restrict__ edata,
                           int n_edges) {
  int e = blockIdx.x * blockDim.x + threadIdx.x;
  if (e < n_edges) {
    int d = dst[e];
    int pos = atomicAdd(&cursor[d], 1);
    int2 v; v.x = src[e]; v.y = e;
    edata[pos] = v;
  }
}

// ---------------------------------------------------------------------------
// agg: wave per node, 4 edges in flight (lane = 16*eo + fo, float4 per lane)
// ---------------------------------------------------------------------------
__global__ void agg_kernel(const float* __restrict__ h, const int* __restrict__ row_ptr,
                           const int2* __restrict__ edata, float* __restrict__ h_agg,
                           int n_nodes) {
  int wid  = (blockIdx.x * blockDim.x + threadIdx.x) >> 6;
  int lane = threadIdx.x & 63;
  int eo = lane >> 4;   // edge slot in group of 4
  int fo = lane & 15;   // float4 slot in row
  if (wid >= n_nodes) return;
  int beg = row_ptr[wid], end = row_ptr[wid + 1];
  float4 acc = {0.f, 0.f, 0.f, 0.f};
  for (int i = beg + eo; i < end; i += 4) {
    int s = edata[i].x;
    float4 v = *reinterpret_cast<const float4*>(h + (size_t)s * OUT_FEATS + fo * 4);
    acc.x += v.x; acc.y += v.y; acc.z += v.z; acc.w += v.w;
  }
#pragma unroll
  for (int off = 16; off < 64; off <<= 1) {
    acc.x += __shfl_xor(acc.x, off, 64);
    acc.y += __shfl_xor(acc.y, off, 64);
    acc.z += __shfl_xor(acc.z, off, 64);
    acc.w += __shfl_xor(acc.w, off, 64);
  }
  if (eo == 0)
    *reinterpret_cast<float4*>(h_agg + (size_t)wid * OUT_FEATS + fo * 4) = acc;
}

// ---------------------------------------------------------------------------
// fused per-node edge softmax, 4 edges in flight.
// After the 4-step xor butterfly every lane of a 16-lane group holds the
// full dot, so score handling needs no extra broadcast.
// ---------------------------------------------------------------------------
__global__ __launch_bounds__(256)
void softmax_kernel(const float* __restrict__ h_agg, const int* __restrict__ row_ptr,
                    const int2* __restrict__ edata,
                    float* __restrict__ e_soft, int n_nodes) {
  __shared__ float ebuf[4][MAXD];
  int wid  = (blockIdx.x * blockDim.x + threadIdx.x) >> 6;
  int lane = threadIdx.x & 63;
  int lw   = threadIdx.x >> 6;
  int eo = lane >> 4;
  int fo = lane & 15;
  if (wid >= n_nodes) return;
  int beg = row_ptr[wid], end = row_ptr[wid + 1];
  int deg = end - beg;
  if (deg == 0) return;

  // tanh of this node's h_agg row, float4 slice per lane (same across eo groups)
  float4 td = *reinterpret_cast<const float4*>(h_agg + (size_t)wid * OUT_FEATS + fo * 4);
  float4 t4;
  t4.x = tanhf(td.x); t4.y = tanhf(td.y); t4.z = tanhf(td.z); t4.w = tanhf(td.w);

  if (deg <= MAXD) {
    for (int i0 = 0; i0 < deg; i0 += 4) {
      int e = i0 + eo;
      int idx = beg + (e < deg ? e : deg - 1);  // clamp; dup gather harmless
      int s = edata[idx].x;
      float4 v = *reinterpret_cast<const float4*>(h_agg + (size_t)s * OUT_FEATS + fo * 4);
      float d = v.x * t4.x + v.y * t4.y + v.z * t4.z + v.w * t4.w;
#pragma unroll
      for (int off = 1; off < 16; off <<= 1) d += __shfl_xor(d, off, 64);
      if (fo == 0 && e < deg) {
        d = d > 0.f ? d : NEG_SLOPE * d;
        ebuf[lw][e] = d;
      }
    }
    float mx = -INFINITY;
    for (int i = lane; i < deg; i += 64) mx = fmaxf(mx, ebuf[lw][i]);
#pragma unroll
    for (int off = 32; off > 0; off >>= 1) mx = fmaxf(mx, __shfl_xor(mx, off, 64));
    float sum = 0.f;
    for (int i = lane; i < deg; i += 64) {
      float ex = expf(ebuf[lw][i] - mx);
      ebuf[lw][i] = ex;
      sum += ex;
    }
#pragma unroll
    for (int off = 32; off > 0; off >>= 1) sum += __shfl_xor(sum, off, 64);
    float inv = 1.f / sum;
    for (int i = lane; i < deg; i += 64) e_soft[edata[beg + i].y] = ebuf[lw][i] * inv;
  } else {
    // recompute fallback (statistically never hit with Poisson(16) degrees)
    float mx = -INFINITY;
    for (int i0 = 0; i0 < deg; i0 += 4) {
      int e = i0 + eo;
      int idx = beg + (e < deg ? e : deg - 1);
      int s = edata[idx].x;
      float4 v = *reinterpret_cast<const float4*>(h_agg + (size_t)s * OUT_FEATS + fo * 4);
      float d = v.x * t4.x + v.y * t4.y + v.z * t4.z + v.w * t4.w;
#pragma unroll
      for (int off = 1; off < 16; off <<= 1) d += __shfl_xor(d, off, 64);
      d = d > 0.f ? d : NEG_SLOPE * d;
      if (e >= deg) d = -INFINITY;
#pragma unroll
      for (int off = 16; off < 64; off <<= 1) d = fmaxf(d, __shfl_xor(d, off, 64));
      mx = fmaxf(mx, d);
    }
    float sum = 0.f;
    for (int i0 = 0; i0 < deg; i0 += 4) {
      int e = i0 + eo;
      int idx = beg + (e < deg ? e : deg - 1);
      int s = edata[idx].x;
      float4 v = *reinterpret_cast<const float4*>(h_agg + (size_t)s * OUT_FEATS + fo * 4);
      float d = v.x * t4.x + v.y * t4.y + v.z * t4.z + v.w * t4.w;
#pragma unroll
      for (int off = 1; off < 16; off <<= 1) d += __shfl_xor(d, off, 64);
      d = d > 0.f ? d : NEG_SLOPE * d;
      float ex = (e < deg) ? expf(d - mx) : 0.f;
#pragma unroll
      for (int off = 16; off < 64; off <<= 1) ex += __shfl_xor(ex, off, 64);
      sum += ex;
    }
    float inv = 1.f / sum;
    for (int i0 = 0; i0 < deg; i0 += 4) {
      int e = i0 + eo;
      int idx = beg + (e < deg ? e : deg - 1);
      int s = edata[idx].x;
      float4 v = *reinterpret_cast<const float4*>(h_agg + (size_t)s * OUT_FEATS + fo * 4);
      float d = v.x * t4.x + v.y * t4.y + v.z * t4.z + v.w * t4.w;
#pragma unroll
      for (int off = 1; off < 16; off <<= 1) d += __shfl_xor(d, off, 64);
      d = d > 0.f ? d : NEG_SLOPE * d;
      if (fo == 0 && e < deg) e_soft[edata[idx].y] = expf(d - mx) * inv;
    }
  }
}

extern "C" void kernel_launch(void* const* d_in, const int* in_sizes, int n_in,
                              void* d_out, int out_size, void* d_ws, size_t ws_size,
                              hipStream_t stream) {
  const float* feat = (const float*)d_in[0];
  const float* W    = (const float*)d_in[1];
  const int*   src  = (const int*)d_in[2];
  const int*   dst  = (const int*)d_in[3];
  const int n_nodes = in_sizes[0] / IN_FEATS;
  const int n_edges = in_sizes[2];

  // Output layout: [h_agg (N*64) | e_soft (E)]
  float* h_agg  = (float*)d_out;
  float* e_soft = (float*)d_out + (size_t)n_nodes * OUT_FEATS;

  // Workspace: [h (N*64 f32) | deg (N) | row_ptr (N+1) | cursor (N) | bsum (1024) | edata (2*E ints)]
  float* h      = (float*)d_ws;
  int* deg      = (int*)(h + (size_t)n_nodes * OUT_FEATS);
  int* row_ptr  = deg + n_nodes;
  int* cursor   = row_ptr + (n_nodes + 1);
  int* bsum     = cursor + n_nodes;
  int2* edata   = (int2*)(bsum + 1024);

  const int nb = (n_nodes + 255) / 256;   // 391 blocks; scan2 handles nb<=1024
  const int eb = (n_edges + 255) / 256;
  const int wb = (n_nodes * 64 + 255) / 256;  // wave-per-node grids

  hipMemsetAsync(deg, 0, (size_t)n_nodes * sizeof(int), stream);

  gemm_h_kernel<<<(n_nodes + 255) / 256, 256, 0, stream>>>(feat, W, h, n_nodes);

  hist_kernel<<<eb, 256, 0, stream>>>(dst, deg, n_edges);
  scan1_kernel<<<nb, 256, 0, stream>>>(deg, bsum, n_nodes);
  scan2_kernel<<<1, 1024, 0, stream>>>(bsum, nb);
  scan3_kernel<<<nb, 256, 0, stream>>>(deg, bsum, row_ptr, cursor, n_nodes, n_edges);
  bin_kernel<<<eb, 256, 0, stream>>>(src, dst, cursor, edata, n_edges);

  agg_kernel<<<wb, 256, 0, stream>>>(h, row_ptr, edata, h_agg, n_nodes);
  softmax_kernel<<<wb, 256, 0, stream>>>(h_agg, row_ptr, edata, e_soft, n_nodes);
}